// Round 6
// baseline (525.210 us; speedup 1.0000x reference)
//
#include <hip/hip_runtime.h>
#include <math.h>

#define BB 16
#define NN 4096
#define MM 1024
#define KNN 32
#define R2 0.04f
#define EPSV 1e-5f
#define S1f ((float)(BB * MM * KNN))
#define S3f ((float)(BB * MM))

typedef __attribute__((ext_vector_type(8))) short short8;
typedef __attribute__((ext_vector_type(4))) short short4v;
typedef __attribute__((ext_vector_type(4))) float f32x4;

__device__ __forceinline__ short f2b(float x) {
    union { float f; unsigned u; } v; v.f = x;
    unsigned r = v.u + 0x7fffu + ((v.u >> 16) & 1u);
    return (short)(r >> 16);
}
__device__ __forceinline__ float gelu_t(float x) {  // tanh-approx (inner layers)
    float u = 0.7978845608f * x * (1.f + 0.044715f * x * x);
    float t = 1.f - 2.f / (__expf(2.f * u) + 1.f);
    return 0.5f * x * (1.f + t);
}
__device__ __forceinline__ float gelu_e(float x) {  // exact (final output)
    return 0.5f * x * (1.f + erff(x * 0.7071067811865475f));
}
__device__ __forceinline__ f32x4 zero4() { f32x4 z = {0.f, 0.f, 0.f, 0.f}; return z; }
__device__ __forceinline__ f32x4 mfma(short8 a, short8 b, f32x4 c) {
    return __builtin_amdgcn_mfma_f32_16x16x32_bf16(a, b, c, 0, 0, 0);
}
__device__ __forceinline__ short8 pack8(f32x4 a, f32x4 b) {
    short8 r;
    r[0] = f2b(a[0]); r[1] = f2b(a[1]); r[2] = f2b(a[2]); r[3] = f2b(a[3]);
    r[4] = f2b(b[0]); r[5] = f2b(b[1]); r[6] = f2b(b[2]); r[7] = f2b(b[3]);
    return r;
}
__device__ __forceinline__ short8 ld8(const short* p) {  // LDS 8B-aligned pair load
    short4v a = *(const short4v*)p;
    short4v b = *(const short4v*)(p + 4);
    return __builtin_shufflevector(a, b, 0, 1, 2, 3, 4, 5, 6, 7);
}

// ---------------- ball query: one query per wave ----------------
__global__ __launch_bounds__(256) void k_ballquery(const float* __restrict__ src_xyz,
                                                   const float* __restrict__ xyz,
                                                   int* __restrict__ gidx) {
    __shared__ float sx[NN], sy[NN], sz[NN];
    int t = threadIdx.x;
    int lane = t & 63, w = t >> 6;
    int q0 = blockIdx.x * 16;
    int b = q0 >> 10;
    const float* sp = src_xyz + (size_t)b * NN * 3;
    for (int i = t; i < NN * 3; i += 256) {
        float v = sp[i];
        int j = i / 3, d = i - j * 3;
        if (d == 0) sx[j] = v;
        else if (d == 1) sy[j] = v;
        else sz[j] = v;
    }
    __syncthreads();
#pragma unroll
    for (int qi = 0; qi < 4; ++qi) {
        int q = q0 + w * 4 + qi;
        int m = q & 1023;
        float qx = xyz[((size_t)b * MM + m) * 3 + 0];
        float qy = xyz[((size_t)b * MM + m) * 3 + 1];
        float qz = xyz[((size_t)b * MM + m) * 3 + 2];
        int* outp = gidx + (size_t)q * KNN;
        int cnt = 0, firstj = -1;
        for (int j0 = 0; j0 < NN && cnt < KNN; j0 += 64) {
            int j = j0 + lane;
            float dx = qx - sx[j];
            float dy = qy - sy[j];
            float dz = qz - sz[j];
            bool hit = (dx * dx + dy * dy + dz * dz) <= R2;
            unsigned long long mask = __ballot(hit);
            if (hit) {
                int rank = cnt + __popcll(mask & ((1ull << lane) - 1ull));
                if (rank < KNN) outp[rank] = j;
            }
            if (firstj < 0 && mask != 0ull) firstj = j0 + __ffsll((long long)mask) - 1;
            cnt += __popcll(mask);
        }
        if (cnt < KNN) {
            int fj = (firstj < 0) ? 0 : firstj;
            for (int k = cnt + lane; k < KNN; k += 64) outp[k] = fj;
        }
    }
}

// ---------------- prep: src_x -> bf16; weights -> bf16 (w1 col-reordered, K-padded) ----------------
// w1b cols: 0..63 = orig 3..66 (src_x part), 64..66 = orig 0..2 (xyz), 67..95 = 0
__global__ __launch_bounds__(256) void k_prep(const float* __restrict__ src_x,
                                              const float* __restrict__ w1,
                                              const float* __restrict__ w2,
                                              const float* __restrict__ w3,
                                              short* __restrict__ src_xb,
                                              short* __restrict__ w1b,
                                              short* __restrict__ w2b,
                                              short* __restrict__ w3b) {
    int i = blockIdx.x * 256 + threadIdx.x;
    if (i < 524288) {  // BB*NN*64/8
        const f32x4* p = (const f32x4*)(src_x + (size_t)i * 8);
        *(short8*)(src_xb + (size_t)i * 8) = pack8(p[0], p[1]);
    } else {
        int j = i - 524288;
        if (j < 6144) {
            int n = j / 96, k = j % 96;
            float v = 0.f;
            if (k < 64) v = w1[n * 67 + 3 + k];
            else if (k < 67) v = w1[n * 67 + (k - 64)];
            w1b[j] = f2b(v);
        } else if (j < 14336) {
            w2b[j - 6144] = f2b(w2[j - 6144]);
        } else if (j < 47104) {
            w3b[j - 14336] = f2b(w3[j - 14336]);
        }
    }
}

// Per-lane direct A-frag fetch for layer1: row = w*16+ln of this block's 64 rows.
// f0 = src_x cols qq*8..+8, f1 = cols 32+qq*8..+8, f2 = cxyz (qq==0 lanes) else 0.
#define FETCH_FRAGS                                                                    \
    int row = w * 16 + ln;                                                             \
    int gg = g0 + (row >> 5), m = gg & 1023;                                           \
    int j = gidx[(size_t)gg * KNN + (row & 31)];                                       \
    const short* xp = src_xb + ((size_t)b * NN + j) * 64;                              \
    short8 f0 = *(const short8*)(xp + qq * 8);                                         \
    short8 f1 = *(const short8*)(xp + 32 + qq * 8);                                    \
    short8 f2 = {0, 0, 0, 0, 0, 0, 0, 0};                                              \
    if (qq == 0) {                                                                     \
        const float* spp = src_xyz + ((size_t)b * NN + j) * 3;                         \
        const float* qp = xyz + ((size_t)b * MM + m) * 3;                              \
        f2[0] = f2b(spp[0] - qp[0]);                                                   \
        f2[1] = f2b(spp[1] - qp[1]);                                                   \
        f2[2] = f2b(spp[2] - qp[2]);                                                   \
    }

// L1 MFMA: acc1[nf], D rows=samples(qq*4+jj), cols=channel(nf*16+ln)
#define L1_MFMA(acc1)                                                                  \
    _Pragma("unroll")                                                                  \
    for (int nf = 0; nf < 4; ++nf) acc1[nf] = zero4();                                 \
    _Pragma("unroll")                                                                  \
    for (int nf = 0; nf < 4; ++nf) {                                                   \
        short8 bw = *(const short8*)(w1b + (nf * 16 + ln) * 96 + qq * 8);              \
        acc1[nf] = mfma(f0, bw, acc1[nf]);                                             \
    }                                                                                  \
    _Pragma("unroll")                                                                  \
    for (int nf = 0; nf < 4; ++nf) {                                                   \
        short8 bw = *(const short8*)(w1b + (nf * 16 + ln) * 96 + 32 + qq * 8);         \
        acc1[nf] = mfma(f1, bw, acc1[nf]);                                             \
    }                                                                                  \
    _Pragma("unroll")                                                                  \
    for (int nf = 0; nf < 4; ++nf) {                                                   \
        short8 bw = *(const short8*)(w1b + (nf * 16 + ln) * 96 + 64 + qq * 8);         \
        acc1[nf] = mfma(f2, bw, acc1[nf]);                                             \
    }

// ---------------- stats1: column stats of pre-h1 (64 rows/block) ----------------
__global__ __launch_bounds__(256, 6) void k_s1(const int* __restrict__ gidx,
                                               const float* __restrict__ src_xyz,
                                               const float* __restrict__ xyz,
                                               const short* __restrict__ src_xb,
                                               const short* __restrict__ w1b,
                                               float* __restrict__ stats1) {
    __shared__ float redS[256], redQ[256];
    int t = threadIdx.x, lane = t & 63, w = t >> 6, ln = lane & 15, qq = lane >> 4;
    int g0 = blockIdx.x * 2, b = g0 >> 10;
    FETCH_FRAGS
    f32x4 acc1[4];
    L1_MFMA(acc1)
#pragma unroll
    for (int nf = 0; nf < 4; ++nf) {
        float s = 0.f, q = 0.f;
#pragma unroll
        for (int jj = 0; jj < 4; ++jj) { float v = acc1[nf][jj]; s += v; q += v * v; }
        s += __shfl_xor(s, 16); s += __shfl_xor(s, 32);
        q += __shfl_xor(q, 16); q += __shfl_xor(q, 32);
        if (lane < 16) { redS[w * 64 + nf * 16 + lane] = s; redQ[w * 64 + nf * 16 + lane] = q; }
    }
    __syncthreads();
    if (t < 64) {
        float s = redS[t] + redS[64 + t] + redS[128 + t] + redS[192 + t];
        float q = redQ[t] + redQ[64 + t] + redQ[128 + t] + redQ[192 + t];
        float* st = stats1 + (blockIdx.x & 7) * 128;
        atomicAdd(&st[t], s);
        atomicAdd(&st[64 + t], q);
    }
}

// ---------------- stats2: recompute h1 (BN1+gelu), column stats of pre-h2 ----------------
__global__ __launch_bounds__(256, 6) void k_s2(const int* __restrict__ gidx,
                                               const float* __restrict__ src_xyz,
                                               const float* __restrict__ xyz,
                                               const short* __restrict__ src_xb,
                                               const short* __restrict__ w1b,
                                               const short* __restrict__ w2b,
                                               const float* __restrict__ g1,
                                               const float* __restrict__ b1,
                                               const float* __restrict__ stats1,
                                               float* __restrict__ stats2) {
    __shared__ short h1S[64 * 68];
    __shared__ float sc1L[64], sh1L[64];
    __shared__ float redS[512], redQ[512];
    int t = threadIdx.x, lane = t & 63, w = t >> 6, ln = lane & 15, qq = lane >> 4;
    int g0 = blockIdx.x * 2, b = g0 >> 10;
    FETCH_FRAGS
    if (t < 64) {
        float s = 0.f, sq = 0.f;
#pragma unroll
        for (int r = 0; r < 8; ++r) { s += stats1[r * 128 + t]; sq += stats1[r * 128 + 64 + t]; }
        float mu = s * (1.f / S1f);
        float var = sq * (1.f / S1f) - mu * mu;
        float rs = rsqrtf(var + EPSV);
        float sc = g1[t] * rs;
        sc1L[t] = sc;
        sh1L[t] = b1[t] - mu * sc;
    }
    f32x4 acc1[4];
    L1_MFMA(acc1)
    __syncthreads();  // sc1L ready
#pragma unroll
    for (int nf = 0; nf < 4; ++nf) {
        int col = nf * 16 + ln;
        float sc = sc1L[col], sh = sh1L[col];
#pragma unroll
        for (int jj = 0; jj < 4; ++jj)
            h1S[(w * 16 + qq * 4 + jj) * 68 + col] = f2b(gelu_t(acc1[nf][jj] * sc + sh));
    }
    // L2 (own wave's rows; no barrier)
    short8 hA[2];
#pragma unroll
    for (int kf = 0; kf < 2; ++kf)
        hA[kf] = ld8(h1S + (w * 16 + ln) * 68 + kf * 32 + qq * 8);
    f32x4 acc2[8];
#pragma unroll
    for (int nf = 0; nf < 8; ++nf) acc2[nf] = zero4();
#pragma unroll
    for (int kf = 0; kf < 2; ++kf)
#pragma unroll
        for (int nf = 0; nf < 8; ++nf) {
            short8 bw = *(const short8*)(w2b + (nf * 16 + ln) * 64 + kf * 32 + qq * 8);
            acc2[nf] = mfma(hA[kf], bw, acc2[nf]);
        }
#pragma unroll
    for (int nf = 0; nf < 8; ++nf) {
        float s = 0.f, q = 0.f;
#pragma unroll
        for (int jj = 0; jj < 4; ++jj) { float v = acc2[nf][jj]; s += v; q += v * v; }
        s += __shfl_xor(s, 16); s += __shfl_xor(s, 32);
        q += __shfl_xor(q, 16); q += __shfl_xor(q, 32);
        if (lane < 16) { redS[w * 128 + nf * 16 + lane] = s; redQ[w * 128 + nf * 16 + lane] = q; }
    }
    __syncthreads();
    if (t < 128) {
        float s = redS[t] + redS[128 + t] + redS[256 + t] + redS[384 + t];
        float q = redQ[t] + redQ[128 + t] + redQ[256 + t] + redQ[384 + t];
        float* st = stats2 + (blockIdx.x & 7) * 256;
        atomicAdd(&st[t], s);
        atomicAdd(&st[128 + t], q);
    }
}

// ---------------- k3: recompute h1,h2; einsum3 + max (64 rows, 5 blocks/CU) ----------------
__global__ __launch_bounds__(256, 5) void k3(const int* __restrict__ gidx,
                                             const float* __restrict__ src_xyz,
                                             const float* __restrict__ xyz,
                                             const short* __restrict__ src_xb,
                                             const short* __restrict__ w1b,
                                             const short* __restrict__ w2b,
                                             const short* __restrict__ w3b,
                                             const float* __restrict__ g1,
                                             const float* __restrict__ b1,
                                             const float* __restrict__ g2,
                                             const float* __restrict__ b2,
                                             const float* __restrict__ stats1,
                                             const float* __restrict__ stats2,
                                             float* __restrict__ out) {
    __shared__ short h1S[64 * 68];     // 8.7 KB
    __shared__ short h2S[64 * 136];    // 17.4 KB
    __shared__ float sc1L[64], sh1L[64], sc2L[128], sh2L[128];
    __shared__ float maxS[4][256];     // per-wave 16-row channel max
    int t = threadIdx.x, lane = t & 63, w = t >> 6, ln = lane & 15, qq = lane >> 4;
    int g0 = blockIdx.x * 2, b = g0 >> 10;
    FETCH_FRAGS
    if (t < 64) {
        float s = 0.f, sq = 0.f;
#pragma unroll
        for (int r = 0; r < 8; ++r) { s += stats1[r * 128 + t]; sq += stats1[r * 128 + 64 + t]; }
        float mu = s * (1.f / S1f);
        float var = sq * (1.f / S1f) - mu * mu;
        float rs = rsqrtf(var + EPSV);
        float sc = g1[t] * rs;
        sc1L[t] = sc;
        sh1L[t] = b1[t] - mu * sc;
    }
    if (t < 128) {
        float s = 0.f, sq = 0.f;
#pragma unroll
        for (int r = 0; r < 8; ++r) { s += stats2[r * 256 + t]; sq += stats2[r * 256 + 128 + t]; }
        float mu = s * (1.f / S1f);
        float var = sq * (1.f / S1f) - mu * mu;
        float rs = rsqrtf(var + EPSV);
        float sc = g2[t] * rs;
        sc2L[t] = sc;
        sh2L[t] = b2[t] - mu * sc;
    }
    f32x4 acc1[4];
    L1_MFMA(acc1)
    __syncthreads();  // barrier 1: scales ready
#pragma unroll
    for (int nf = 0; nf < 4; ++nf) {
        int col = nf * 16 + ln;
        float sc = sc1L[col], sh = sh1L[col];
#pragma unroll
        for (int jj = 0; jj < 4; ++jj)
            h1S[(w * 16 + qq * 4 + jj) * 68 + col] = f2b(gelu_t(acc1[nf][jj] * sc + sh));
    }
    // L2 (wave-private rows)
    short8 hA[2];
#pragma unroll
    for (int kf = 0; kf < 2; ++kf)
        hA[kf] = ld8(h1S + (w * 16 + ln) * 68 + kf * 32 + qq * 8);
    f32x4 acc2[8];
#pragma unroll
    for (int nf = 0; nf < 8; ++nf) acc2[nf] = zero4();
#pragma unroll
    for (int kf = 0; kf < 2; ++kf)
#pragma unroll
        for (int nf = 0; nf < 8; ++nf) {
            short8 bw = *(const short8*)(w2b + (nf * 16 + ln) * 64 + kf * 32 + qq * 8);
            acc2[nf] = mfma(hA[kf], bw, acc2[nf]);
        }
#pragma unroll
    for (int nf = 0; nf < 8; ++nf) {
        int col = nf * 16 + ln;
        float sc = sc2L[col], sh = sh2L[col];
#pragma unroll
        for (int jj = 0; jj < 4; ++jj)
            h2S[(w * 16 + qq * 4 + jj) * 136 + col] = f2b(gelu_t(acc2[nf][jj] * sc + sh));
    }
    // L3 (wave-private rows); w3 frags from global (L1/L2-resident)
    short8 h2f[4];
#pragma unroll
    for (int kf = 0; kf < 4; ++kf)
        h2f[kf] = ld8(h2S + (w * 16 + ln) * 136 + kf * 32 + qq * 8);
#pragma unroll
    for (int nc = 0; nc < 4; ++nc) {
        f32x4 acc3[4];
#pragma unroll
        for (int nf = 0; nf < 4; ++nf) acc3[nf] = zero4();
#pragma unroll
        for (int kf = 0; kf < 4; ++kf)
#pragma unroll
            for (int nf = 0; nf < 4; ++nf) {
                short8 bw = *(const short8*)(w3b + (size_t)(nc * 64 + nf * 16 + ln) * 128 + kf * 32 + qq * 8);
                acc3[nf] = mfma(h2f[kf], bw, acc3[nf]);
            }
#pragma unroll
        for (int nf = 0; nf < 4; ++nf) {
            float v = fmaxf(fmaxf(acc3[nf][0], acc3[nf][1]), fmaxf(acc3[nf][2], acc3[nf][3]));
            v = fmaxf(v, __shfl_xor(v, 16));
            v = fmaxf(v, __shfl_xor(v, 32));
            if (lane < 16) maxS[w][nc * 64 + nf * 16 + lane] = v;
        }
    }
    __syncthreads();  // barrier 2: maxS complete
    {
        float m0 = fmaxf(maxS[0][t], maxS[1][t]);
        float m1 = fmaxf(maxS[2][t], maxS[3][t]);
        out[(size_t)g0 * 256 + t] = m0;
        out[(size_t)(g0 + 1) * 256 + t] = m1;
    }
}

// ---------------- stats3 + final BN/GELU ----------------
__global__ __launch_bounds__(256) void k_stats3(const float* __restrict__ out,
                                                float* __restrict__ stats3) {
    int t = threadIdx.x;
    float s = 0.f, q = 0.f;
    const float* p = out + (size_t)blockIdx.x * 128 * 256 + t;
    for (int r = 0; r < 128; ++r) { float v = p[r * 256]; s += v; q += v * v; }
    atomicAdd(&stats3[t], s);
    atomicAdd(&stats3[256 + t], q);
}

__global__ __launch_bounds__(256) void k_bn3(float* __restrict__ out,
                                             const float* __restrict__ stats3,
                                             const float* __restrict__ gl,
                                             const float* __restrict__ bl) {
    int i = blockIdx.x * 256 + threadIdx.x;
    int o = i & 255;
    float mu = stats3[o] * (1.f / S3f);
    float var = stats3[256 + o] * (1.f / S3f) - mu * mu;
    float rs = rsqrtf(var + EPSV);
    float x = out[i];
    out[i] = gelu_e((x - mu) * rs * gl[o] + bl[o]);
}

extern "C" void kernel_launch(void* const* d_in, const int* in_sizes, int n_in,
                              void* d_out, int out_size, void* d_ws, size_t ws_size,
                              hipStream_t stream) {
    const float* src_x   = (const float*)d_in[0];
    const float* src_xyz = (const float*)d_in[1];
    const float* xyz     = (const float*)d_in[2];
    const float* w1      = (const float*)d_in[3];
    const float* g1      = (const float*)d_in[4];
    const float* b1      = (const float*)d_in[5];
    const float* w2      = (const float*)d_in[6];
    const float* g2      = (const float*)d_in[7];
    const float* b2      = (const float*)d_in[8];
    const float* w3      = (const float*)d_in[9];
    const float* gl      = (const float*)d_in[10];
    const float* bl      = (const float*)d_in[11];
    float* out = (float*)d_out;

    int* gidx = (int*)d_ws;                              // 512K ints
    float* statsF = (float*)(gidx + BB * MM * KNN);
    float* stats1 = statsF;          // 8 x (64 sum | 64 sq)
    float* stats2 = statsF + 1024;   // 8 x (128 sum | 128 sq)
    float* stats3 = statsF + 3072;   // 256 sum + 256 sq
    short* wb = (short*)(statsF + 3584);
    short* w1b = wb;                 // [64][96] reordered
    short* w2b = wb + 6144;          // [128][64]
    short* w3b = wb + 14336;         // [256][128]
    short* src_xb = wb + 47104;      // [B][N][64] bf16

    hipMemsetAsync(statsF, 0, 3584 * sizeof(float), stream);
    k_prep<<<2232, 256, 0, stream>>>(src_x, w1, w2, w3, src_xb, w1b, w2b, w3b);
    k_ballquery<<<(BB * MM) / 16, 256, 0, stream>>>(src_xyz, xyz, gidx);
    k_s1<<<(BB * MM) / 2, 256, 0, stream>>>(gidx, src_xyz, xyz, src_xb, w1b, stats1);
    k_s2<<<(BB * MM) / 2, 256, 0, stream>>>(gidx, src_xyz, xyz, src_xb, w1b, w2b, g1, b1,
                                            stats1, stats2);
    k3<<<(BB * MM) / 2, 256, 0, stream>>>(gidx, src_xyz, xyz, src_xb, w1b, w2b, w3b,
                                          g1, b1, g2, b2, stats1, stats2, out);
    k_stats3<<<(BB * MM) / 128, 256, 0, stream>>>(out, stats3);
    k_bn3<<<BB * MM, 256, 0, stream>>>(out, stats3, gl, bl);
}

// Round 8
// 331.793 us; speedup vs baseline: 1.5829x; 1.5829x over previous
//
#include <hip/hip_runtime.h>
#include <math.h>

#define BB 16
#define NN 4096
#define MM 1024
#define KNN 32
#define R2 0.04f
#define EPSV 1e-5f
#define S1f ((float)(BB * MM * KNN))
#define S3f ((float)(BB * MM))

typedef __attribute__((ext_vector_type(8))) short short8;
typedef __attribute__((ext_vector_type(4))) short short4v;
typedef __attribute__((ext_vector_type(4))) float f32x4;

__device__ __forceinline__ short f2b(float x) {
    union { float f; unsigned u; } v; v.f = x;
    unsigned r = v.u + 0x7fffu + ((v.u >> 16) & 1u);
    return (short)(r >> 16);
}
__device__ __forceinline__ float gelu_t(float x) {  // tanh-approx (inner layers)
    float u = 0.7978845608f * x * (1.f + 0.044715f * x * x);
    float t = 1.f - 2.f / (__expf(2.f * u) + 1.f);
    return 0.5f * x * (1.f + t);
}
__device__ __forceinline__ float gelu_e(float x) {  // exact (final output)
    return 0.5f * x * (1.f + erff(x * 0.7071067811865475f));
}
__device__ __forceinline__ f32x4 zero4() { f32x4 z = {0.f, 0.f, 0.f, 0.f}; return z; }
__device__ __forceinline__ f32x4 mfma(short8 a, short8 b, f32x4 c) {
    return __builtin_amdgcn_mfma_f32_16x16x32_bf16(a, b, c, 0, 0, 0);
}
__device__ __forceinline__ short8 pack8(f32x4 a, f32x4 b) {
    short8 r;
    r[0] = f2b(a[0]); r[1] = f2b(a[1]); r[2] = f2b(a[2]); r[3] = f2b(a[3]);
    r[4] = f2b(b[0]); r[5] = f2b(b[1]); r[6] = f2b(b[2]); r[7] = f2b(b[3]);
    return r;
}

// ---------------- ball query: one query per wave ----------------
__global__ __launch_bounds__(256) void k_ballquery(const float* __restrict__ src_xyz,
                                                   const float* __restrict__ xyz,
                                                   int* __restrict__ gidx) {
    __shared__ float sx[NN], sy[NN], sz[NN];
    int t = threadIdx.x;
    int lane = t & 63, w = t >> 6;
    int q0 = blockIdx.x * 16;
    int b = q0 >> 10;
    const float* sp = src_xyz + (size_t)b * NN * 3;
    for (int i = t; i < NN * 3; i += 256) {
        float v = sp[i];
        int j = i / 3, d = i - j * 3;
        if (d == 0) sx[j] = v;
        else if (d == 1) sy[j] = v;
        else sz[j] = v;
    }
    __syncthreads();
#pragma unroll
    for (int qi = 0; qi < 4; ++qi) {
        int q = q0 + w * 4 + qi;
        int m = q & 1023;
        float qx = xyz[((size_t)b * MM + m) * 3 + 0];
        float qy = xyz[((size_t)b * MM + m) * 3 + 1];
        float qz = xyz[((size_t)b * MM + m) * 3 + 2];
        int* outp = gidx + (size_t)q * KNN;
        int cnt = 0, firstj = -1;
        for (int j0 = 0; j0 < NN && cnt < KNN; j0 += 64) {
            int j = j0 + lane;
            float dx = qx - sx[j];
            float dy = qy - sy[j];
            float dz = qz - sz[j];
            bool hit = (dx * dx + dy * dy + dz * dz) <= R2;
            unsigned long long mask = __ballot(hit);
            if (hit) {
                int rank = cnt + __popcll(mask & ((1ull << lane) - 1ull));
                if (rank < KNN) outp[rank] = j;
            }
            if (firstj < 0 && mask != 0ull) firstj = j0 + __ffsll((long long)mask) - 1;
            cnt += __popcll(mask);
        }
        if (cnt < KNN) {
            int fj = (firstj < 0) ? 0 : firstj;
            for (int k = cnt + lane; k < KNN; k += 64) outp[k] = fj;
        }
    }
}

// ---------------- prep: src_x -> bf16; weights -> bf16 (w1 col-reordered, K-padded) ----------------
// w1b cols: 0..63 = orig 3..66 (src_x), 64..66 = orig 0..2 (xyz), 67..95 = 0
__global__ __launch_bounds__(256) void k_prep(const float* __restrict__ src_x,
                                              const float* __restrict__ w1,
                                              const float* __restrict__ w2,
                                              const float* __restrict__ w3,
                                              short* __restrict__ src_xb,
                                              short* __restrict__ w1b,
                                              short* __restrict__ w2b,
                                              short* __restrict__ w3b) {
    int i = blockIdx.x * 256 + threadIdx.x;
    if (i < 524288) {  // BB*NN*64/8
        const f32x4* p = (const f32x4*)(src_x + (size_t)i * 8);
        *(short8*)(src_xb + (size_t)i * 8) = pack8(p[0], p[1]);
    } else {
        int j = i - 524288;
        if (j < 6144) {
            int n = j / 96, k = j % 96;
            float v = 0.f;
            if (k < 64) v = w1[n * 67 + 3 + k];
            else if (k < 67) v = w1[n * 67 + (k - 64)];
            w1b[j] = f2b(v);
        } else if (j < 14336) {
            w2b[j - 6144] = f2b(w2[j - 6144]);
        } else if (j < 47104) {
            w3b[j - 14336] = f2b(w3[j - 14336]);
        }
    }
}

// Per-wave gather into wave-private region R (feat rows stride 72, 16B-aligned).
// Thread (lane u): fills half hf=u&1 (32 cols = 4 x short8) of row r=u>>1;
// hf==0 also writes cxyz + zero pad. Lanes u<8 zero the tail over-read zone [2304..2336).
#define GATHER_WAVE(R)                                                                  \
    {                                                                                   \
        if (lane < 8) { short4v z4 = {0, 0, 0, 0};                                      \
            *(short4v*)((R) + 2304 + lane * 4) = z4; }                                  \
        int r = lane >> 1, hf = lane & 1;                                               \
        int jdx = gidx[(size_t)g * KNN + r];                                            \
        const short8* sp = (const short8*)(src_xb + ((size_t)b * NN + jdx) * 64 + hf * 32); \
        *(short8*)((R) + r * 72 + hf * 32) = sp[0];                                     \
        *(short8*)((R) + r * 72 + hf * 32 + 8) = sp[1];                                 \
        *(short8*)((R) + r * 72 + hf * 32 + 16) = sp[2];                                \
        *(short8*)((R) + r * 72 + hf * 32 + 24) = sp[3];                                \
        if (hf == 0) {                                                                  \
            const float* spp = src_xyz + ((size_t)b * NN + jdx) * 3;                    \
            short4v z;                                                                  \
            z[0] = f2b(spp[0] - qx); z[1] = f2b(spp[1] - qy);                           \
            z[2] = f2b(spp[2] - qz); z[3] = 0;                                          \
            *(short4v*)((R) + r * 72 + 64) = z;                                         \
            short4v z0 = {0, 0, 0, 0};                                                  \
            *(short4v*)((R) + r * 72 + 68) = z0;                                        \
        }                                                                               \
    }

// L1: 6 aligned b128 frag loads + 24 MFMA. acc1[rf][nf]: rows rf*16+qq*4+j, col nf*16+ln.
// kf=2,qq>=1 over-reads land on next-row data / zeroed tail, times ZERO w1b cols 72..95.
#define L1_PHASE(R, acc1)                                                               \
    short8 a1f[2][3];                                                                   \
    _Pragma("unroll")                                                                   \
    for (int rf = 0; rf < 2; ++rf)                                                      \
        _Pragma("unroll")                                                               \
        for (int kf = 0; kf < 3; ++kf)                                                  \
            a1f[rf][kf] = *(const short8*)((R) + (rf * 16 + ln) * 72 + kf * 32 + qq * 8); \
    _Pragma("unroll")                                                                   \
    for (int rf = 0; rf < 2; ++rf)                                                      \
        _Pragma("unroll")                                                               \
        for (int nf = 0; nf < 4; ++nf) acc1[rf][nf] = zero4();                          \
    _Pragma("unroll")                                                                   \
    for (int kf = 0; kf < 3; ++kf)                                                      \
        _Pragma("unroll")                                                               \
        for (int nf = 0; nf < 4; ++nf) {                                                \
            short8 bw = *(const short8*)(w1b + (nf * 16 + ln) * 96 + kf * 32 + qq * 8); \
            acc1[0][nf] = mfma(a1f[0][kf], bw, acc1[0][nf]);                            \
            acc1[1][nf] = mfma(a1f[1][kf], bw, acc1[1][nf]);                            \
        }

// h1 epilogue into R (stride 72, overwrites feat; feat already in regs)
#define H1_EPI(R, acc1)                                                                 \
    _Pragma("unroll")                                                                   \
    for (int rf = 0; rf < 2; ++rf)                                                      \
        _Pragma("unroll")                                                               \
        for (int nf = 0; nf < 4; ++nf) {                                                \
            int col = nf * 16 + ln;                                                     \
            float sc = sc1L[col], sh = sh1L[col];                                       \
            int row0 = rf * 16 + qq * 4;                                                \
            _Pragma("unroll")                                                           \
            for (int jj = 0; jj < 4; ++jj)                                              \
                (R)[(row0 + jj) * 72 + col] = f2b(gelu_t(acc1[rf][nf][jj] * sc + sh));  \
        }

// L2: 4 b128 h1 frag loads + 32 MFMA (w2 from global)
#define L2_PHASE(R, acc2)                                                               \
    short8 hA[2][2];                                                                    \
    _Pragma("unroll")                                                                   \
    for (int rf = 0; rf < 2; ++rf)                                                      \
        _Pragma("unroll")                                                               \
        for (int kf = 0; kf < 2; ++kf)                                                  \
            hA[rf][kf] = *(const short8*)((R) + (rf * 16 + ln) * 72 + kf * 32 + qq * 8); \
    _Pragma("unroll")                                                                   \
    for (int rf = 0; rf < 2; ++rf)                                                      \
        _Pragma("unroll")                                                               \
        for (int nf = 0; nf < 8; ++nf) acc2[rf][nf] = zero4();                          \
    _Pragma("unroll")                                                                   \
    for (int kf = 0; kf < 2; ++kf)                                                      \
        _Pragma("unroll")                                                               \
        for (int nf = 0; nf < 8; ++nf) {                                                \
            short8 bw = *(const short8*)(w2b + (nf * 16 + ln) * 64 + kf * 32 + qq * 8); \
            acc2[0][nf] = mfma(hA[0][kf], bw, acc2[0][nf]);                             \
            acc2[1][nf] = mfma(hA[1][kf], bw, acc2[1][nf]);                             \
        }

// ---------------- stats1: column stats of pre-h1 (128 rows/block, wave-private LDS) ----------------
__global__ __launch_bounds__(256, 6) void k_s1(const int* __restrict__ gidx,
                                               const float* __restrict__ src_xyz,
                                               const float* __restrict__ xyz,
                                               const short* __restrict__ src_xb,
                                               const short* __restrict__ w1b,
                                               float* __restrict__ stats1) {
    __shared__ short wbuf[4][2336];
    __shared__ float redS[256], redQ[256];
    int t = threadIdx.x, lane = t & 63, w = t >> 6, ln = lane & 15, qq = lane >> 4;
    int g = blockIdx.x * 4 + w, b = g >> 10, m = g & 1023;
    float qx = xyz[((size_t)b * MM + m) * 3 + 0];
    float qy = xyz[((size_t)b * MM + m) * 3 + 1];
    float qz = xyz[((size_t)b * MM + m) * 3 + 2];
    short* R = wbuf[w];
    GATHER_WAVE(R)
    f32x4 acc1[2][4];
    L1_PHASE(R, acc1)
#pragma unroll
    for (int nf = 0; nf < 4; ++nf) {
        float s = 0.f, q = 0.f;
#pragma unroll
        for (int rf = 0; rf < 2; ++rf)
#pragma unroll
            for (int jj = 0; jj < 4; ++jj) { float v = acc1[rf][nf][jj]; s += v; q += v * v; }
        s += __shfl_xor(s, 16); s += __shfl_xor(s, 32);
        q += __shfl_xor(q, 16); q += __shfl_xor(q, 32);
        if (lane < 16) { redS[w * 64 + nf * 16 + lane] = s; redQ[w * 64 + nf * 16 + lane] = q; }
    }
    __syncthreads();
    if (t < 64) {
        float s = redS[t] + redS[64 + t] + redS[128 + t] + redS[192 + t];
        float q = redQ[t] + redQ[64 + t] + redQ[128 + t] + redQ[192 + t];
        float* st = stats1 + (blockIdx.x & 7) * 128;
        atomicAdd(&st[t], s);
        atomicAdd(&st[64 + t], q);
    }
}

// ---------------- stats2: recompute h1, column stats of pre-h2 ----------------
__global__ __launch_bounds__(256, 4) void k_s2(const int* __restrict__ gidx,
                                               const float* __restrict__ src_xyz,
                                               const float* __restrict__ xyz,
                                               const short* __restrict__ src_xb,
                                               const short* __restrict__ w1b,
                                               const short* __restrict__ w2b,
                                               const float* __restrict__ g1,
                                               const float* __restrict__ b1,
                                               const float* __restrict__ stats1,
                                               float* __restrict__ stats2) {
    __shared__ short wbuf[4][2336];
    __shared__ float sc1L[64], sh1L[64];
    __shared__ float redS[512], redQ[512];
    int t = threadIdx.x, lane = t & 63, w = t >> 6, ln = lane & 15, qq = lane >> 4;
    int g = blockIdx.x * 4 + w, b = g >> 10, m = g & 1023;
    float qx = xyz[((size_t)b * MM + m) * 3 + 0];
    float qy = xyz[((size_t)b * MM + m) * 3 + 1];
    float qz = xyz[((size_t)b * MM + m) * 3 + 2];
    short* R = wbuf[w];
    GATHER_WAVE(R)
    if (t < 64) {
        float s = 0.f, sq = 0.f;
#pragma unroll
        for (int r = 0; r < 8; ++r) { s += stats1[r * 128 + t]; sq += stats1[r * 128 + 64 + t]; }
        float mu = s * (1.f / S1f);
        float var = sq * (1.f / S1f) - mu * mu;
        float rs = rsqrtf(var + EPSV);
        float sc = g1[t] * rs;
        sc1L[t] = sc;
        sh1L[t] = b1[t] - mu * sc;
    }
    f32x4 acc1[2][4];
    L1_PHASE(R, acc1)
    __syncthreads();  // sc1L ready
    H1_EPI(R, acc1)
    f32x4 acc2[2][8];
    L2_PHASE(R, acc2)
#pragma unroll
    for (int nf = 0; nf < 8; ++nf) {
        float s = 0.f, q = 0.f;
#pragma unroll
        for (int rf = 0; rf < 2; ++rf)
#pragma unroll
            for (int jj = 0; jj < 4; ++jj) { float v = acc2[rf][nf][jj]; s += v; q += v * v; }
        s += __shfl_xor(s, 16); s += __shfl_xor(s, 32);
        q += __shfl_xor(q, 16); q += __shfl_xor(q, 32);
        if (lane < 16) { redS[w * 128 + nf * 16 + lane] = s; redQ[w * 128 + nf * 16 + lane] = q; }
    }
    __syncthreads();
    if (t < 128) {
        float s = redS[t] + redS[128 + t] + redS[256 + t] + redS[384 + t];
        float q = redQ[t] + redQ[128 + t] + redQ[256 + t] + redQ[384 + t];
        float* st = stats2 + (blockIdx.x & 7) * 256;
        atomicAdd(&st[t], s);
        atomicAdd(&st[128 + t], q);
    }
}

// ---------------- k3: recompute h1,h2; einsum3 + max (1 barrier, 36KB LDS) ----------------
__global__ __launch_bounds__(256, 4) void k3(const int* __restrict__ gidx,
                                             const float* __restrict__ src_xyz,
                                             const float* __restrict__ xyz,
                                             const short* __restrict__ src_xb,
                                             const short* __restrict__ w1b,
                                             const short* __restrict__ w2b,
                                             const short* __restrict__ w3b,
                                             const float* __restrict__ g1,
                                             const float* __restrict__ b1,
                                             const float* __restrict__ g2,
                                             const float* __restrict__ b2,
                                             const float* __restrict__ stats1,
                                             const float* __restrict__ stats2,
                                             float* __restrict__ out) {
    __shared__ short wbuf[4][4352];    // per-wave: feat(72) -> h1(72) -> h2(136)
    __shared__ float sc1L[64], sh1L[64], sc2L[128], sh2L[128];
    int t = threadIdx.x, lane = t & 63, w = t >> 6, ln = lane & 15, qq = lane >> 4;
    int g = blockIdx.x * 4 + w, b = g >> 10, m = g & 1023;
    float qx = xyz[((size_t)b * MM + m) * 3 + 0];
    float qy = xyz[((size_t)b * MM + m) * 3 + 1];
    float qz = xyz[((size_t)b * MM + m) * 3 + 2];
    short* R = wbuf[w];
    GATHER_WAVE(R)
    if (t < 64) {
        float s = 0.f, sq = 0.f;
#pragma unroll
        for (int r = 0; r < 8; ++r) { s += stats1[r * 128 + t]; sq += stats1[r * 128 + 64 + t]; }
        float mu = s * (1.f / S1f);
        float var = sq * (1.f / S1f) - mu * mu;
        float rs = rsqrtf(var + EPSV);
        float sc = g1[t] * rs;
        sc1L[t] = sc;
        sh1L[t] = b1[t] - mu * sc;
    }
    if (t < 128) {
        float s = 0.f, sq = 0.f;
#pragma unroll
        for (int r = 0; r < 8; ++r) { s += stats2[r * 256 + t]; sq += stats2[r * 256 + 128 + t]; }
        float mu = s * (1.f / S1f);
        float var = sq * (1.f / S1f) - mu * mu;
        float rs = rsqrtf(var + EPSV);
        float sc = g2[t] * rs;
        sc2L[t] = sc;
        sh2L[t] = b2[t] - mu * sc;
    }
    f32x4 acc1[2][4];
    L1_PHASE(R, acc1)
    __syncthreads();  // the only barrier: scales ready
    H1_EPI(R, acc1)
    f32x4 acc2[2][8];
    L2_PHASE(R, acc2)
    // h2 epilogue (stride 136; h1 frags already consumed)
#pragma unroll
    for (int rf = 0; rf < 2; ++rf)
#pragma unroll
        for (int nf = 0; nf < 8; ++nf) {
            int col = nf * 16 + ln;
            float sc = sc2L[col], sh = sh2L[col];
            int row0 = rf * 16 + qq * 4;
#pragma unroll
            for (int jj = 0; jj < 4; ++jj)
                R[(row0 + jj) * 136 + col] = f2b(gelu_t(acc2[rf][nf][jj] * sc + sh));
        }
    // L3: 8 aligned b128 h2 frag loads; w3 frags from global; max over 32 rows in-wave
    short8 h2f[2][4];
#pragma unroll
    for (int rf = 0; rf < 2; ++rf)
#pragma unroll
        for (int kf = 0; kf < 4; ++kf)
            h2f[rf][kf] = *(const short8*)(R + (rf * 16 + ln) * 136 + kf * 32 + qq * 8);
#pragma unroll
    for (int nc = 0; nc < 4; ++nc) {
        f32x4 acc3[2][4];
#pragma unroll
        for (int rf = 0; rf < 2; ++rf)
#pragma unroll
            for (int nf = 0; nf < 4; ++nf) acc3[rf][nf] = zero4();
#pragma unroll
        for (int kf = 0; kf < 4; ++kf)
#pragma unroll
            for (int nf = 0; nf < 4; ++nf) {
                short8 bw = *(const short8*)(w3b + (size_t)(nc * 64 + nf * 16 + ln) * 128 + kf * 32 + qq * 8);
                acc3[0][nf] = mfma(h2f[0][kf], bw, acc3[0][nf]);
                acc3[1][nf] = mfma(h2f[1][kf], bw, acc3[1][nf]);
            }
#pragma unroll
        for (int nf = 0; nf < 4; ++nf) {
            float v = fmaxf(fmaxf(fmaxf(acc3[0][nf][0], acc3[0][nf][1]), fmaxf(acc3[0][nf][2], acc3[0][nf][3])),
                            fmaxf(fmaxf(acc3[1][nf][0], acc3[1][nf][1]), fmaxf(acc3[1][nf][2], acc3[1][nf][3])));
            v = fmaxf(v, __shfl_xor(v, 16));
            v = fmaxf(v, __shfl_xor(v, 32));
            if (lane < 16) out[(size_t)g * 256 + nc * 64 + nf * 16 + lane] = v;
        }
    }
}

// ---------------- stats3 + final BN/GELU ----------------
__global__ __launch_bounds__(256) void k_stats3(const float* __restrict__ out,
                                                float* __restrict__ stats3) {
    int t = threadIdx.x;
    float s = 0.f, q = 0.f;
    const float* p = out + (size_t)blockIdx.x * 128 * 256 + t;
    for (int r = 0; r < 128; ++r) { float v = p[r * 256]; s += v; q += v * v; }
    atomicAdd(&stats3[t], s);
    atomicAdd(&stats3[256 + t], q);
}

__global__ __launch_bounds__(256) void k_bn3(float* __restrict__ out,
                                             const float* __restrict__ stats3,
                                             const float* __restrict__ gl,
                                             const float* __restrict__ bl) {
    int i = blockIdx.x * 256 + threadIdx.x;
    int o = i & 255;
    float mu = stats3[o] * (1.f / S3f);
    float var = stats3[256 + o] * (1.f / S3f) - mu * mu;
    float rs = rsqrtf(var + EPSV);
    float x = out[i];
    out[i] = gelu_e((x - mu) * rs * gl[o] + bl[o]);
}

extern "C" void kernel_launch(void* const* d_in, const int* in_sizes, int n_in,
                              void* d_out, int out_size, void* d_ws, size_t ws_size,
                              hipStream_t stream) {
    const float* src_x   = (const float*)d_in[0];
    const float* src_xyz = (const float*)d_in[1];
    const float* xyz     = (const float*)d_in[2];
    const float* w1      = (const float*)d_in[3];
    const float* g1      = (const float*)d_in[4];
    const float* b1      = (const float*)d_in[5];
    const float* w2      = (const float*)d_in[6];
    const float* g2      = (const float*)d_in[7];
    const float* b2      = (const float*)d_in[8];
    const float* w3      = (const float*)d_in[9];
    const float* gl      = (const float*)d_in[10];
    const float* bl      = (const float*)d_in[11];
    float* out = (float*)d_out;

    int* gidx = (int*)d_ws;                              // 512K ints
    float* statsF = (float*)(gidx + BB * MM * KNN);
    float* stats1 = statsF;          // 8 x (64 sum | 64 sq)
    float* stats2 = statsF + 1024;   // 8 x (128 sum | 128 sq)
    float* stats3 = statsF + 3072;   // 256 sum + 256 sq
    short* wb = (short*)(statsF + 3584);
    short* w1b = wb;                 // [64][96] reordered
    short* w2b = wb + 6144;          // [128][64]
    short* w3b = wb + 14336;         // [256][128]
    short* src_xb = wb + 47104;      // [B][N][64] bf16

    hipMemsetAsync(statsF, 0, 3584 * sizeof(float), stream);
    k_prep<<<2232, 256, 0, stream>>>(src_x, w1, w2, w3, src_xb, w1b, w2b, w3b);
    k_ballquery<<<(BB * MM) / 16, 256, 0, stream>>>(src_xyz, xyz, gidx);
    k_s1<<<(BB * MM) / 4, 256, 0, stream>>>(gidx, src_xyz, xyz, src_xb, w1b, stats1);
    k_s2<<<(BB * MM) / 4, 256, 0, stream>>>(gidx, src_xyz, xyz, src_xb, w1b, w2b, g1, b1,
                                            stats1, stats2);
    k3<<<(BB * MM) / 4, 256, 0, stream>>>(gidx, src_xyz, xyz, src_xb, w1b, w2b, w3b,
                                          g1, b1, g2, b2, stats1, stats2, out);
    k_stats3<<<(BB * MM) / 128, 256, 0, stream>>>(out, stats3);
    k_bn3<<<BB * MM, 256, 0, stream>>>(out, stats3, gl, bl);
}

// Round 9
// 322.126 us; speedup vs baseline: 1.6305x; 1.0300x over previous
//
#include <hip/hip_runtime.h>
#include <math.h>

#define BB 16
#define NN 4096
#define MM 1024
#define KNN 32
#define R2 0.04f
#define EPSV 1e-5f
#define S1f ((float)(BB * MM * KNN))
#define S3f ((float)(BB * MM))

typedef __attribute__((ext_vector_type(8))) short short8;
typedef __attribute__((ext_vector_type(4))) short short4v;
typedef __attribute__((ext_vector_type(4))) float f32x4;

__device__ __forceinline__ short f2b(float x) {
    union { float f; unsigned u; } v; v.f = x;
    unsigned r = v.u + 0x7fffu + ((v.u >> 16) & 1u);
    return (short)(r >> 16);
}
__device__ __forceinline__ float b2f(short s) {
    union { unsigned u; float f; } v; v.u = ((unsigned)(unsigned short)s) << 16;
    return v.f;
}
__device__ __forceinline__ float gelu_t(float x) {  // tanh-approx (inner layers)
    float u = 0.7978845608f * x * (1.f + 0.044715f * x * x);
    float t = 1.f - 2.f / (__expf(2.f * u) + 1.f);
    return 0.5f * x * (1.f + t);
}
__device__ __forceinline__ float gelu_e(float x) {  // exact (final output)
    return 0.5f * x * (1.f + erff(x * 0.7071067811865475f));
}
__device__ __forceinline__ f32x4 zero4() { f32x4 z = {0.f, 0.f, 0.f, 0.f}; return z; }
__device__ __forceinline__ f32x4 mfma(short8 a, short8 b, f32x4 c) {
    return __builtin_amdgcn_mfma_f32_16x16x32_bf16(a, b, c, 0, 0, 0);
}
__device__ __forceinline__ short8 pack8(f32x4 a, f32x4 b) {
    short8 r;
    r[0] = f2b(a[0]); r[1] = f2b(a[1]); r[2] = f2b(a[2]); r[3] = f2b(a[3]);
    r[4] = f2b(b[0]); r[5] = f2b(b[1]); r[6] = f2b(b[2]); r[7] = f2b(b[3]);
    return r;
}

// ---------------- ball query: one query per wave ----------------
__global__ __launch_bounds__(256) void k_ballquery(const float* __restrict__ src_xyz,
                                                   const float* __restrict__ xyz,
                                                   int* __restrict__ gidx) {
    __shared__ float sx[NN], sy[NN], sz[NN];
    int t = threadIdx.x;
    int lane = t & 63, w = t >> 6;
    int q0 = blockIdx.x * 16;
    int b = q0 >> 10;
    const float* sp = src_xyz + (size_t)b * NN * 3;
    for (int i = t; i < NN * 3; i += 256) {
        float v = sp[i];
        int j = i / 3, d = i - j * 3;
        if (d == 0) sx[j] = v;
        else if (d == 1) sy[j] = v;
        else sz[j] = v;
    }
    __syncthreads();
#pragma unroll
    for (int qi = 0; qi < 4; ++qi) {
        int q = q0 + w * 4 + qi;
        int m = q & 1023;
        float qx = xyz[((size_t)b * MM + m) * 3 + 0];
        float qy = xyz[((size_t)b * MM + m) * 3 + 1];
        float qz = xyz[((size_t)b * MM + m) * 3 + 2];
        int* outp = gidx + (size_t)q * KNN;
        int cnt = 0, firstj = -1;
        for (int j0 = 0; j0 < NN && cnt < KNN; j0 += 64) {
            int j = j0 + lane;
            float dx = qx - sx[j];
            float dy = qy - sy[j];
            float dz = qz - sz[j];
            bool hit = (dx * dx + dy * dy + dz * dz) <= R2;
            unsigned long long mask = __ballot(hit);
            if (hit) {
                int rank = cnt + __popcll(mask & ((1ull << lane) - 1ull));
                if (rank < KNN) outp[rank] = j;
            }
            if (firstj < 0 && mask != 0ull) firstj = j0 + __ffsll((long long)mask) - 1;
            cnt += __popcll(mask);
        }
        if (cnt < KNN) {
            int fj = (firstj < 0) ? 0 : firstj;
            for (int k = cnt + lane; k < KNN; k += 64) outp[k] = fj;
        }
    }
}

// ---------------- prep: src_x -> bf16; weights -> bf16 (w1 col-reordered, K-padded) ----------------
__global__ __launch_bounds__(256) void k_prep(const float* __restrict__ src_x,
                                              const float* __restrict__ w1,
                                              const float* __restrict__ w2,
                                              const float* __restrict__ w3,
                                              short* __restrict__ src_xb,
                                              short* __restrict__ w1b,
                                              short* __restrict__ w2b,
                                              short* __restrict__ w3b) {
    int i = blockIdx.x * 256 + threadIdx.x;
    if (i < 524288) {  // BB*NN*64/8
        const f32x4* p = (const f32x4*)(src_x + (size_t)i * 8);
        *(short8*)(src_xb + (size_t)i * 8) = pack8(p[0], p[1]);
    } else {
        int j = i - 524288;
        if (j < 6144) {
            int n = j / 96, k = j % 96;
            float v = 0.f;
            if (k < 64) v = w1[n * 67 + 3 + k];
            else if (k < 67) v = w1[n * 67 + (k - 64)];
            w1b[j] = f2b(v);
        } else if (j < 14336) {
            w2b[j - 6144] = f2b(w2[j - 6144]);
        } else if (j < 47104) {
            w3b[j - 14336] = f2b(w3[j - 14336]);
        }
    }
}

// Per-wave gather into wave-private region R (feat rows stride 72, 16B-aligned).
#define GATHER_WAVE(R)                                                                  \
    {                                                                                   \
        if (lane < 8) { short4v z4 = {0, 0, 0, 0};                                      \
            *(short4v*)((R) + 2304 + lane * 4) = z4; }                                  \
        int r = lane >> 1, hf = lane & 1;                                               \
        int jdx = gidx[(size_t)g * KNN + r];                                            \
        const short8* sp = (const short8*)(src_xb + ((size_t)b * NN + jdx) * 64 + hf * 32); \
        *(short8*)((R) + r * 72 + hf * 32) = sp[0];                                     \
        *(short8*)((R) + r * 72 + hf * 32 + 8) = sp[1];                                 \
        *(short8*)((R) + r * 72 + hf * 32 + 16) = sp[2];                                \
        *(short8*)((R) + r * 72 + hf * 32 + 24) = sp[3];                                \
        if (hf == 0) {                                                                  \
            const float* spp = src_xyz + ((size_t)b * NN + jdx) * 3;                    \
            short4v z;                                                                  \
            z[0] = f2b(spp[0] - qx); z[1] = f2b(spp[1] - qy);                           \
            z[2] = f2b(spp[2] - qz); z[3] = 0;                                          \
            *(short4v*)((R) + r * 72 + 64) = z;                                         \
            short4v z0 = {0, 0, 0, 0};                                                  \
            *(short4v*)((R) + r * 72 + 68) = z0;                                        \
        }                                                                               \
    }

// L1: 6 aligned b128 frag loads + 24 MFMA.
#define L1_PHASE(R, acc1)                                                               \
    short8 a1f[2][3];                                                                   \
    _Pragma("unroll")                                                                   \
    for (int rf = 0; rf < 2; ++rf)                                                      \
        _Pragma("unroll")                                                               \
        for (int kf = 0; kf < 3; ++kf)                                                  \
            a1f[rf][kf] = *(const short8*)((R) + (rf * 16 + ln) * 72 + kf * 32 + qq * 8); \
    _Pragma("unroll")                                                                   \
    for (int rf = 0; rf < 2; ++rf)                                                      \
        _Pragma("unroll")                                                               \
        for (int nf = 0; nf < 4; ++nf) acc1[rf][nf] = zero4();                          \
    _Pragma("unroll")                                                                   \
    for (int kf = 0; kf < 3; ++kf)                                                      \
        _Pragma("unroll")                                                               \
        for (int nf = 0; nf < 4; ++nf) {                                                \
            short8 bw = *(const short8*)(w1b + (nf * 16 + ln) * 96 + kf * 32 + qq * 8); \
            acc1[0][nf] = mfma(a1f[0][kf], bw, acc1[0][nf]);                            \
            acc1[1][nf] = mfma(a1f[1][kf], bw, acc1[1][nf]);                            \
        }

// h1 epilogue into R (stride 72)
#define H1_EPI(R, acc1)                                                                 \
    _Pragma("unroll")                                                                   \
    for (int rf = 0; rf < 2; ++rf)                                                      \
        _Pragma("unroll")                                                               \
        for (int nf = 0; nf < 4; ++nf) {                                                \
            int col = nf * 16 + ln;                                                     \
            float sc = sc1L[col], sh = sh1L[col];                                       \
            int row0 = rf * 16 + qq * 4;                                                \
            _Pragma("unroll")                                                           \
            for (int jj = 0; jj < 4; ++jj)                                              \
                (R)[(row0 + jj) * 72 + col] = f2b(gelu_t(acc1[rf][nf][jj] * sc + sh));  \
        }

// L2: 4 b128 h1 frag loads + 32 MFMA (w2 from global)
#define L2_PHASE(R, acc2)                                                               \
    short8 hA[2][2];                                                                    \
    _Pragma("unroll")                                                                   \
    for (int rf = 0; rf < 2; ++rf)                                                      \
        _Pragma("unroll")                                                               \
        for (int kf = 0; kf < 2; ++kf)                                                  \
            hA[rf][kf] = *(const short8*)((R) + (rf * 16 + ln) * 72 + kf * 32 + qq * 8); \
    _Pragma("unroll")                                                                   \
    for (int rf = 0; rf < 2; ++rf)                                                      \
        _Pragma("unroll")                                                               \
        for (int nf = 0; nf < 8; ++nf) acc2[rf][nf] = zero4();                          \
    _Pragma("unroll")                                                                   \
    for (int kf = 0; kf < 2; ++kf)                                                      \
        _Pragma("unroll")                                                               \
        for (int nf = 0; nf < 8; ++nf) {                                                \
            short8 bw = *(const short8*)(w2b + (nf * 16 + ln) * 64 + kf * 32 + qq * 8); \
            acc2[0][nf] = mfma(hA[0][kf], bw, acc2[0][nf]);                             \
            acc2[1][nf] = mfma(hA[1][kf], bw, acc2[1][nf]);                             \
        }

// ---------------- stats1 ----------------
__global__ __launch_bounds__(256, 6) void k_s1(const int* __restrict__ gidx,
                                               const float* __restrict__ src_xyz,
                                               const float* __restrict__ xyz,
                                               const short* __restrict__ src_xb,
                                               const short* __restrict__ w1b,
                                               float* __restrict__ stats1) {
    __shared__ short wbuf[4][2336];
    __shared__ float redS[256], redQ[256];
    int t = threadIdx.x, lane = t & 63, w = t >> 6, ln = lane & 15, qq = lane >> 4;
    int g = blockIdx.x * 4 + w, b = g >> 10, m = g & 1023;
    float qx = xyz[((size_t)b * MM + m) * 3 + 0];
    float qy = xyz[((size_t)b * MM + m) * 3 + 1];
    float qz = xyz[((size_t)b * MM + m) * 3 + 2];
    short* R = wbuf[w];
    GATHER_WAVE(R)
    f32x4 acc1[2][4];
    L1_PHASE(R, acc1)
#pragma unroll
    for (int nf = 0; nf < 4; ++nf) {
        float s = 0.f, q = 0.f;
#pragma unroll
        for (int rf = 0; rf < 2; ++rf)
#pragma unroll
            for (int jj = 0; jj < 4; ++jj) { float v = acc1[rf][nf][jj]; s += v; q += v * v; }
        s += __shfl_xor(s, 16); s += __shfl_xor(s, 32);
        q += __shfl_xor(q, 16); q += __shfl_xor(q, 32);
        if (lane < 16) { redS[w * 64 + nf * 16 + lane] = s; redQ[w * 64 + nf * 16 + lane] = q; }
    }
    __syncthreads();
    if (t < 64) {
        float s = redS[t] + redS[64 + t] + redS[128 + t] + redS[192 + t];
        float q = redQ[t] + redQ[64 + t] + redQ[128 + t] + redQ[192 + t];
        float* st = stats1 + (blockIdx.x & 7) * 128;
        atomicAdd(&st[t], s);
        atomicAdd(&st[64 + t], q);
    }
}

// ---------------- stats2: recompute h1, stats of pre-h2; optionally store pre-h2 ----------------
__global__ __launch_bounds__(256, 4) void k_s2(const int* __restrict__ gidx,
                                               const float* __restrict__ src_xyz,
                                               const float* __restrict__ xyz,
                                               const short* __restrict__ src_xb,
                                               const short* __restrict__ w1b,
                                               const short* __restrict__ w2b,
                                               const float* __restrict__ g1,
                                               const float* __restrict__ b1,
                                               const float* __restrict__ stats1,
                                               float* __restrict__ stats2,
                                               short* __restrict__ h2p) {
    __shared__ short wbuf[4][2336];
    __shared__ float sc1L[64], sh1L[64];
    __shared__ float redS[512], redQ[512];
    int t = threadIdx.x, lane = t & 63, w = t >> 6, ln = lane & 15, qq = lane >> 4;
    int g = blockIdx.x * 4 + w, b = g >> 10, m = g & 1023;
    float qx = xyz[((size_t)b * MM + m) * 3 + 0];
    float qy = xyz[((size_t)b * MM + m) * 3 + 1];
    float qz = xyz[((size_t)b * MM + m) * 3 + 2];
    short* R = wbuf[w];
    GATHER_WAVE(R)
    if (t < 64) {
        float s = 0.f, sq = 0.f;
#pragma unroll
        for (int r = 0; r < 8; ++r) { s += stats1[r * 128 + t]; sq += stats1[r * 128 + 64 + t]; }
        float mu = s * (1.f / S1f);
        float var = sq * (1.f / S1f) - mu * mu;
        float rs = rsqrtf(var + EPSV);
        float sc = g1[t] * rs;
        sc1L[t] = sc;
        sh1L[t] = b1[t] - mu * sc;
    }
    f32x4 acc1[2][4];
    L1_PHASE(R, acc1)
    __syncthreads();  // sc1L ready
    H1_EPI(R, acc1)
    f32x4 acc2[2][8];
    L2_PHASE(R, acc2)
    if (h2p) {  // store pre-BN h2 (bf16) for the GEMM-only k3n
#pragma unroll
        for (int rf = 0; rf < 2; ++rf)
#pragma unroll
            for (int nf = 0; nf < 8; ++nf) {
                int col = nf * 16 + ln;
                size_t row0 = (size_t)g * 32 + rf * 16 + qq * 4;
#pragma unroll
                for (int jj = 0; jj < 4; ++jj)
                    h2p[(row0 + jj) * 128 + col] = f2b(acc2[rf][nf][jj]);
            }
    }
#pragma unroll
    for (int nf = 0; nf < 8; ++nf) {
        float s = 0.f, q = 0.f;
#pragma unroll
        for (int rf = 0; rf < 2; ++rf)
#pragma unroll
            for (int jj = 0; jj < 4; ++jj) { float v = acc2[rf][nf][jj]; s += v; q += v * v; }
        s += __shfl_xor(s, 16); s += __shfl_xor(s, 32);
        q += __shfl_xor(q, 16); q += __shfl_xor(q, 32);
        if (lane < 16) { redS[w * 128 + nf * 16 + lane] = s; redQ[w * 128 + nf * 16 + lane] = q; }
    }
    __syncthreads();
    if (t < 128) {
        float s = redS[t] + redS[128 + t] + redS[256 + t] + redS[384 + t];
        float q = redQ[t] + redQ[128 + t] + redQ[256 + t] + redQ[384 + t];
        float* st = stats2 + (blockIdx.x & 7) * 256;
        atomicAdd(&st[t], s);
        atomicAdd(&st[128 + t], q);
    }
}

// ---------------- k3n: pure GEMM from materialized pre-h2 + max ----------------
// Per wave: one group (32 rows). Frags loaded straight from h2p; BN2+gelu in regs;
// w3 LDS-staged in 64-row chunks. No gather, no recompute.
__global__ __launch_bounds__(256, 6) void k3n(const short* __restrict__ h2p,
                                              const short* __restrict__ w3b,
                                              const float* __restrict__ g2,
                                              const float* __restrict__ b2,
                                              const float* __restrict__ stats2,
                                              float* __restrict__ out) {
    __shared__ short w3S[64 * 136];   // 17.4 KB
    __shared__ float sc2L[128], sh2L[128];
    int t = threadIdx.x, lane = t & 63, w = t >> 6, ln = lane & 15, qq = lane >> 4;
    int g = blockIdx.x * 4 + w;
    // raw pre-h2 frags: rows ln, ln+16 of this group's 32 rows
    const short* hp = h2p + (size_t)g * 32 * 128;
    short8 frag[2][4];
#pragma unroll
    for (int rf = 0; rf < 2; ++rf)
#pragma unroll
        for (int kf = 0; kf < 4; ++kf)
            frag[rf][kf] = *(const short8*)(hp + (rf * 16 + ln) * 128 + kf * 32 + qq * 8);
    if (t < 128) {
        float s = 0.f, sq = 0.f;
#pragma unroll
        for (int r = 0; r < 8; ++r) { s += stats2[r * 256 + t]; sq += stats2[r * 256 + 128 + t]; }
        float mu = s * (1.f / S1f);
        float var = sq * (1.f / S1f) - mu * mu;
        float rs = rsqrtf(var + EPSV);
        float sc = g2[t] * rs;
        sc2L[t] = sc;
        sh2L[t] = b2[t] - mu * sc;
    }
    __syncthreads();  // sc2L ready
    // BN2 + gelu in registers
#pragma unroll
    for (int rf = 0; rf < 2; ++rf)
#pragma unroll
        for (int kf = 0; kf < 4; ++kf) {
            int c0 = kf * 32 + qq * 8;
            f32x4 sa = *(const f32x4*)(sc2L + c0);
            f32x4 sb = *(const f32x4*)(sc2L + c0 + 4);
            f32x4 ha = *(const f32x4*)(sh2L + c0);
            f32x4 hb = *(const f32x4*)(sh2L + c0 + 4);
            short8 r = frag[rf][kf];
            short8 o;
#pragma unroll
            for (int e = 0; e < 4; ++e)
                o[e] = f2b(gelu_t(b2f(r[e]) * sa[e] + ha[e]));
#pragma unroll
            for (int e = 0; e < 4; ++e)
                o[e + 4] = f2b(gelu_t(b2f(r[e + 4]) * sb[e] + hb[e]));
            frag[rf][kf] = o;
        }
#pragma unroll
    for (int nc = 0; nc < 4; ++nc) {
        __syncthreads();
        {   // stage 64-row w3 chunk: thread t -> row t>>2, col-chunk (t&3)*32
            const short8* sp = (const short8*)(w3b + (size_t)(nc * 64 + (t >> 2)) * 128 + (t & 3) * 32);
            short8* dp = (short8*)(w3S + (t >> 2) * 136 + (t & 3) * 32);
            dp[0] = sp[0]; dp[1] = sp[1]; dp[2] = sp[2]; dp[3] = sp[3];
        }
        __syncthreads();
        f32x4 acc3[2][4];
#pragma unroll
        for (int rf = 0; rf < 2; ++rf)
#pragma unroll
            for (int nf = 0; nf < 4; ++nf) acc3[rf][nf] = zero4();
#pragma unroll
        for (int kf = 0; kf < 4; ++kf)
#pragma unroll
            for (int nf = 0; nf < 4; ++nf) {
                short8 bw = *(const short8*)(w3S + (nf * 16 + ln) * 136 + kf * 32 + qq * 8);
                acc3[0][nf] = mfma(frag[0][kf], bw, acc3[0][nf]);
                acc3[1][nf] = mfma(frag[1][kf], bw, acc3[1][nf]);
            }
#pragma unroll
        for (int nf = 0; nf < 4; ++nf) {
            float v = fmaxf(fmaxf(fmaxf(acc3[0][nf][0], acc3[0][nf][1]), fmaxf(acc3[0][nf][2], acc3[0][nf][3])),
                            fmaxf(fmaxf(acc3[1][nf][0], acc3[1][nf][1]), fmaxf(acc3[1][nf][2], acc3[1][nf][3])));
            v = fmaxf(v, __shfl_xor(v, 16));
            v = fmaxf(v, __shfl_xor(v, 32));
            if (lane < 16) out[(size_t)g * 256 + nc * 64 + nf * 16 + lane] = v;
        }
    }
}

// ---------------- k3 fallback (r8 structure, used when ws too small) ----------------
__global__ __launch_bounds__(256, 4) void k3(const int* __restrict__ gidx,
                                             const float* __restrict__ src_xyz,
                                             const float* __restrict__ xyz,
                                             const short* __restrict__ src_xb,
                                             const short* __restrict__ w1b,
                                             const short* __restrict__ w2b,
                                             const short* __restrict__ w3b,
                                             const float* __restrict__ g1,
                                             const float* __restrict__ b1,
                                             const float* __restrict__ g2,
                                             const float* __restrict__ b2,
                                             const float* __restrict__ stats1,
                                             const float* __restrict__ stats2,
                                             float* __restrict__ out) {
    __shared__ short wbuf[4][4352];
    __shared__ float sc1L[64], sh1L[64], sc2L[128], sh2L[128];
    int t = threadIdx.x, lane = t & 63, w = t >> 6, ln = lane & 15, qq = lane >> 4;
    int g = blockIdx.x * 4 + w, b = g >> 10, m = g & 1023;
    float qx = xyz[((size_t)b * MM + m) * 3 + 0];
    float qy = xyz[((size_t)b * MM + m) * 3 + 1];
    float qz = xyz[((size_t)b * MM + m) * 3 + 2];
    short* R = wbuf[w];
    GATHER_WAVE(R)
    if (t < 64) {
        float s = 0.f, sq = 0.f;
#pragma unroll
        for (int r = 0; r < 8; ++r) { s += stats1[r * 128 + t]; sq += stats1[r * 128 + 64 + t]; }
        float mu = s * (1.f / S1f);
        float var = sq * (1.f / S1f) - mu * mu;
        float rs = rsqrtf(var + EPSV);
        float sc = g1[t] * rs;
        sc1L[t] = sc;
        sh1L[t] = b1[t] - mu * sc;
    }
    if (t < 128) {
        float s = 0.f, sq = 0.f;
#pragma unroll
        for (int r = 0; r < 8; ++r) { s += stats2[r * 256 + t]; sq += stats2[r * 256 + 128 + t]; }
        float mu = s * (1.f / S1f);
        float var = sq * (1.f / S1f) - mu * mu;
        float rs = rsqrtf(var + EPSV);
        float sc = g2[t] * rs;
        sc2L[t] = sc;
        sh2L[t] = b2[t] - mu * sc;
    }
    f32x4 acc1[2][4];
    L1_PHASE(R, acc1)
    __syncthreads();
    H1_EPI(R, acc1)
    f32x4 acc2[2][8];
    L2_PHASE(R, acc2)
#pragma unroll
    for (int rf = 0; rf < 2; ++rf)
#pragma unroll
        for (int nf = 0; nf < 8; ++nf) {
            int col = nf * 16 + ln;
            float sc = sc2L[col], sh = sh2L[col];
            int row0 = rf * 16 + qq * 4;
#pragma unroll
            for (int jj = 0; jj < 4; ++jj)
                R[(row0 + jj) * 136 + col] = f2b(gelu_t(acc2[rf][nf][jj] * sc + sh));
        }
    short8 h2f[2][4];
#pragma unroll
    for (int rf = 0; rf < 2; ++rf)
#pragma unroll
        for (int kf = 0; kf < 4; ++kf)
            h2f[rf][kf] = *(const short8*)(R + (rf * 16 + ln) * 136 + kf * 32 + qq * 8);
#pragma unroll
    for (int nc = 0; nc < 4; ++nc) {
        f32x4 acc3[2][4];
#pragma unroll
        for (int rf = 0; rf < 2; ++rf)
#pragma unroll
            for (int nf = 0; nf < 4; ++nf) acc3[rf][nf] = zero4();
#pragma unroll
        for (int kf = 0; kf < 4; ++kf)
#pragma unroll
            for (int nf = 0; nf < 4; ++nf) {
                short8 bw = *(const short8*)(w3b + (size_t)(nc * 64 + nf * 16 + ln) * 128 + kf * 32 + qq * 8);
                acc3[0][nf] = mfma(h2f[0][kf], bw, acc3[0][nf]);
                acc3[1][nf] = mfma(h2f[1][kf], bw, acc3[1][nf]);
            }
#pragma unroll
        for (int nf = 0; nf < 4; ++nf) {
            float v = fmaxf(fmaxf(fmaxf(acc3[0][nf][0], acc3[0][nf][1]), fmaxf(acc3[0][nf][2], acc3[0][nf][3])),
                            fmaxf(fmaxf(acc3[1][nf][0], acc3[1][nf][1]), fmaxf(acc3[1][nf][2], acc3[1][nf][3])));
            v = fmaxf(v, __shfl_xor(v, 16));
            v = fmaxf(v, __shfl_xor(v, 32));
            if (lane < 16) out[(size_t)g * 256 + nc * 64 + nf * 16 + lane] = v;
        }
    }
}

// ---------------- stats3 + final BN/GELU ----------------
__global__ __launch_bounds__(256) void k_stats3(const float* __restrict__ out,
                                                float* __restrict__ stats3) {
    int t = threadIdx.x;
    float s = 0.f, q = 0.f;
    const float* p = out + (size_t)blockIdx.x * 128 * 256 + t;
    for (int r = 0; r < 128; ++r) { float v = p[r * 256]; s += v; q += v * v; }
    atomicAdd(&stats3[t], s);
    atomicAdd(&stats3[256 + t], q);
}

__global__ __launch_bounds__(256) void k_bn3(float* __restrict__ out,
                                             const float* __restrict__ stats3,
                                             const float* __restrict__ gl,
                                             const float* __restrict__ bl) {
    int i = blockIdx.x * 256 + threadIdx.x;
    int o = i & 255;
    float mu = stats3[o] * (1.f / S3f);
    float var = stats3[256 + o] * (1.f / S3f) - mu * mu;
    float rs = rsqrtf(var + EPSV);
    float x = out[i];
    out[i] = gelu_e((x - mu) * rs * gl[o] + bl[o]);
}

extern "C" void kernel_launch(void* const* d_in, const int* in_sizes, int n_in,
                              void* d_out, int out_size, void* d_ws, size_t ws_size,
                              hipStream_t stream) {
    const float* src_x   = (const float*)d_in[0];
    const float* src_xyz = (const float*)d_in[1];
    const float* xyz     = (const float*)d_in[2];
    const float* w1      = (const float*)d_in[3];
    const float* g1      = (const float*)d_in[4];
    const float* b1      = (const float*)d_in[5];
    const float* w2      = (const float*)d_in[6];
    const float* g2      = (const float*)d_in[7];
    const float* b2      = (const float*)d_in[8];
    const float* w3      = (const float*)d_in[9];
    const float* gl      = (const float*)d_in[10];
    const float* bl      = (const float*)d_in[11];
    float* out = (float*)d_out;

    int* gidx = (int*)d_ws;                              // 2 MB
    float* statsF = (float*)(gidx + BB * MM * KNN);
    float* stats1 = statsF;          // 8 x (64 sum | 64 sq)
    float* stats2 = statsF + 1024;   // 8 x (128 sum | 128 sq)
    float* stats3 = statsF + 3072;   // 256 sum + 256 sq
    short* wb = (short*)(statsF + 3584);
    short* w1b = wb;                 // [64][96] reordered
    short* w2b = wb + 6144;          // [128][64]
    short* w3b = wb + 14336;         // [256][128]
    short* src_xb = wb + 47104;      // [B][N][64] bf16  (ends ~10.6 MB)
    // materialized pre-BN h2 at fixed 16 MB offset (128 MB)
    short* h2p = (short*)((char*)d_ws + (size_t)(16u << 20));
    const size_t NEED = (size_t)(16u << 20) + (size_t)BB * MM * KNN * 128 * sizeof(short);
    bool big = ws_size >= NEED;

    hipMemsetAsync(statsF, 0, 3584 * sizeof(float), stream);
    k_prep<<<2232, 256, 0, stream>>>(src_x, w1, w2, w3, src_xb, w1b, w2b, w3b);
    k_ballquery<<<(BB * MM) / 16, 256, 0, stream>>>(src_xyz, xyz, gidx);
    k_s1<<<(BB * MM) / 4, 256, 0, stream>>>(gidx, src_xyz, xyz, src_xb, w1b, stats1);
    k_s2<<<(BB * MM) / 4, 256, 0, stream>>>(gidx, src_xyz, xyz, src_xb, w1b, w2b, g1, b1,
                                            stats1, stats2, big ? h2p : (short*)nullptr);
    if (big) {
        k3n<<<(BB * MM) / 4, 256, 0, stream>>>(h2p, w3b, g2, b2, stats2, out);
    } else {
        k3<<<(BB * MM) / 4, 256, 0, stream>>>(gidx, src_xyz, xyz, src_xb, w1b, w2b, w3b,
                                              g1, b1, g2, b2, stats1, stats2, out);
    }
    k_stats3<<<(BB * MM) / 128, 256, 0, stream>>>(out, stats3);
    k_bn3<<<BB * MM, 256, 0, stream>>>(out, stats3, gl, bl);
}

// Round 10
// 311.285 us; speedup vs baseline: 1.6872x; 1.0348x over previous
//
#include <hip/hip_runtime.h>
#include <math.h>

#define BB 16
#define NN 4096
#define MM 1024
#define KNN 32
#define R2 0.04f
#define EPSV 1e-5f
#define S1f ((float)(BB * MM * KNN))
#define S3f ((float)(BB * MM))

typedef __attribute__((ext_vector_type(8))) short short8;
typedef __attribute__((ext_vector_type(4))) short short4v;
typedef __attribute__((ext_vector_type(4))) float f32x4;

__device__ __forceinline__ short f2b(float x) {
    union { float f; unsigned u; } v; v.f = x;
    unsigned r = v.u + 0x7fffu + ((v.u >> 16) & 1u);
    return (short)(r >> 16);
}
__device__ __forceinline__ float b2f(short s) {
    union { unsigned u; float f; } v; v.u = ((unsigned)(unsigned short)s) << 16;
    return v.f;
}
__device__ __forceinline__ float gelu_t(float x) {  // tanh-approx (inner layers)
    float u = 0.7978845608f * x * (1.f + 0.044715f * x * x);
    float t = 1.f - 2.f / (__expf(2.f * u) + 1.f);
    return 0.5f * x * (1.f + t);
}
__device__ __forceinline__ float gelu_e(float x) {  // exact (final output)
    return 0.5f * x * (1.f + erff(x * 0.7071067811865475f));
}
__device__ __forceinline__ f32x4 zero4() { f32x4 z = {0.f, 0.f, 0.f, 0.f}; return z; }
__device__ __forceinline__ f32x4 mfma(short8 a, short8 b, f32x4 c) {
    return __builtin_amdgcn_mfma_f32_16x16x32_bf16(a, b, c, 0, 0, 0);
}
__device__ __forceinline__ short8 pack8(f32x4 a, f32x4 b) {
    short8 r;
    r[0] = f2b(a[0]); r[1] = f2b(a[1]); r[2] = f2b(a[2]); r[3] = f2b(a[3]);
    r[4] = f2b(b[0]); r[5] = f2b(b[1]); r[6] = f2b(b[2]); r[7] = f2b(b[3]);
    return r;
}

// ---------------- ball query: one query per wave ----------------
__global__ __launch_bounds__(256) void k_ballquery(const float* __restrict__ src_xyz,
                                                   const float* __restrict__ xyz,
                                                   int* __restrict__ gidx) {
    __shared__ float sx[NN], sy[NN], sz[NN];
    int t = threadIdx.x;
    int lane = t & 63, w = t >> 6;
    int q0 = blockIdx.x * 16;
    int b = q0 >> 10;
    const float* sp = src_xyz + (size_t)b * NN * 3;
    for (int i = t; i < NN * 3; i += 256) {
        float v = sp[i];
        int j = i / 3, d = i - j * 3;
        if (d == 0) sx[j] = v;
        else if (d == 1) sy[j] = v;
        else sz[j] = v;
    }
    __syncthreads();
#pragma unroll
    for (int qi = 0; qi < 4; ++qi) {
        int q = q0 + w * 4 + qi;
        int m = q & 1023;
        float qx = xyz[((size_t)b * MM + m) * 3 + 0];
        float qy = xyz[((size_t)b * MM + m) * 3 + 1];
        float qz = xyz[((size_t)b * MM + m) * 3 + 2];
        int* outp = gidx + (size_t)q * KNN;
        int cnt = 0, firstj = -1;
        for (int j0 = 0; j0 < NN && cnt < KNN; j0 += 64) {
            int j = j0 + lane;
            float dx = qx - sx[j];
            float dy = qy - sy[j];
            float dz = qz - sz[j];
            bool hit = (dx * dx + dy * dy + dz * dz) <= R2;
            unsigned long long mask = __ballot(hit);
            if (hit) {
                int rank = cnt + __popcll(mask & ((1ull << lane) - 1ull));
                if (rank < KNN) outp[rank] = j;
            }
            if (firstj < 0 && mask != 0ull) firstj = j0 + __ffsll((long long)mask) - 1;
            cnt += __popcll(mask);
        }
        if (cnt < KNN) {
            int fj = (firstj < 0) ? 0 : firstj;
            for (int k = cnt + lane; k < KNN; k += 64) outp[k] = fj;
        }
    }
}

// ---------------- prep: src_x -> bf16; weights -> bf16 (w1 col-reordered, K-padded) ----------------
__global__ __launch_bounds__(256) void k_prep(const float* __restrict__ src_x,
                                              const float* __restrict__ w1,
                                              const float* __restrict__ w2,
                                              const float* __restrict__ w3,
                                              short* __restrict__ src_xb,
                                              short* __restrict__ w1b,
                                              short* __restrict__ w2b,
                                              short* __restrict__ w3b) {
    int i = blockIdx.x * 256 + threadIdx.x;
    if (i < 524288) {  // BB*NN*64/8
        const f32x4* p = (const f32x4*)(src_x + (size_t)i * 8);
        *(short8*)(src_xb + (size_t)i * 8) = pack8(p[0], p[1]);
    } else {
        int j = i - 524288;
        if (j < 6144) {
            int n = j / 96, k = j % 96;
            float v = 0.f;
            if (k < 64) v = w1[n * 67 + 3 + k];
            else if (k < 67) v = w1[n * 67 + (k - 64)];
            w1b[j] = f2b(v);
        } else if (j < 14336) {
            w2b[j - 6144] = f2b(w2[j - 6144]);
        } else if (j < 47104) {
            w3b[j - 14336] = f2b(w3[j - 14336]);
        }
    }
}

// Per-wave gather into wave-private region R (feat rows stride 72, 16B-aligned).
#define GATHER_WAVE(R)                                                                  \
    {                                                                                   \
        if (lane < 8) { short4v z4 = {0, 0, 0, 0};                                      \
            *(short4v*)((R) + 2304 + lane * 4) = z4; }                                  \
        int r = lane >> 1, hf = lane & 1;                                               \
        int jdx = gidx[(size_t)g * KNN + r];                                            \
        const short8* sp = (const short8*)(src_xb + ((size_t)b * NN + jdx) * 64 + hf * 32); \
        *(short8*)((R) + r * 72 + hf * 32) = sp[0];                                     \
        *(short8*)((R) + r * 72 + hf * 32 + 8) = sp[1];                                 \
        *(short8*)((R) + r * 72 + hf * 32 + 16) = sp[2];                                \
        *(short8*)((R) + r * 72 + hf * 32 + 24) = sp[3];                                \
        if (hf == 0) {                                                                  \
            const float* spp = src_xyz + ((size_t)b * NN + jdx) * 3;                    \
            short4v z;                                                                  \
            z[0] = f2b(spp[0] - qx); z[1] = f2b(spp[1] - qy);                           \
            z[2] = f2b(spp[2] - qz); z[3] = 0;                                          \
            *(short4v*)((R) + r * 72 + 64) = z;                                         \
            short4v z0 = {0, 0, 0, 0};                                                  \
            *(short4v*)((R) + r * 72 + 68) = z0;                                        \
        }                                                                               \
    }

// L1: 6 aligned b128 frag loads + 24 MFMA.
#define L1_PHASE(R, acc1)                                                               \
    short8 a1f[2][3];                                                                   \
    _Pragma("unroll")                                                                   \
    for (int rf = 0; rf < 2; ++rf)                                                      \
        _Pragma("unroll")                                                               \
        for (int kf = 0; kf < 3; ++kf)                                                  \
            a1f[rf][kf] = *(const short8*)((R) + (rf * 16 + ln) * 72 + kf * 32 + qq * 8); \
    _Pragma("unroll")                                                                   \
    for (int rf = 0; rf < 2; ++rf)                                                      \
        _Pragma("unroll")                                                               \
        for (int nf = 0; nf < 4; ++nf) acc1[rf][nf] = zero4();                          \
    _Pragma("unroll")                                                                   \
    for (int kf = 0; kf < 3; ++kf)                                                      \
        _Pragma("unroll")                                                               \
        for (int nf = 0; nf < 4; ++nf) {                                                \
            short8 bw = *(const short8*)(w1b + (nf * 16 + ln) * 96 + kf * 32 + qq * 8); \
            acc1[0][nf] = mfma(a1f[0][kf], bw, acc1[0][nf]);                            \
            acc1[1][nf] = mfma(a1f[1][kf], bw, acc1[1][nf]);                            \
        }

// Decode packed pre-h1 (hv[4]) -> BN1 + gelu -> LDS tile R (stride 72, wave-private)
#define H1_FROM_PACKED(R, hv)                                                           \
    _Pragma("unroll")                                                                   \
    for (int i = 0; i < 4; ++i) {                                                       \
        int rf = i >> 1;                                                                \
        int c0 = (i & 1) * 32 + ln, c1 = c0 + 16;                                       \
        int r0 = rf * 16 + qq * 4;                                                      \
        float s0 = sc1L[c0], h0 = sh1L[c0];                                             \
        float s1v = sc1L[c1], h1v = sh1L[c1];                                           \
        _Pragma("unroll")                                                               \
        for (int e = 0; e < 4; ++e) {                                                   \
            (R)[(r0 + e) * 72 + c0] = f2b(gelu_t(b2f(hv[i][e]) * s0 + h0));             \
            (R)[(r0 + e) * 72 + c1] = f2b(gelu_t(b2f(hv[i][e + 4]) * s1v + h1v));       \
        }                                                                               \
    }

// L2: 4 b128 h1 frag loads + 32 MFMA (w2 from global)
#define L2_PHASE(R, acc2)                                                               \
    short8 hA[2][2];                                                                    \
    _Pragma("unroll")                                                                   \
    for (int rf = 0; rf < 2; ++rf)                                                      \
        _Pragma("unroll")                                                               \
        for (int kf = 0; kf < 2; ++kf)                                                  \
            hA[rf][kf] = *(const short8*)((R) + (rf * 16 + ln) * 72 + kf * 32 + qq * 8); \
    _Pragma("unroll")                                                                   \
    for (int rf = 0; rf < 2; ++rf)                                                      \
        _Pragma("unroll")                                                               \
        for (int nf = 0; nf < 8; ++nf) acc2[rf][nf] = zero4();                          \
    _Pragma("unroll")                                                                   \
    for (int kf = 0; kf < 2; ++kf)                                                      \
        _Pragma("unroll")                                                               \
        for (int nf = 0; nf < 8; ++nf) {                                                \
            short8 bw = *(const short8*)(w2b + (nf * 16 + ln) * 64 + kf * 32 + qq * 8); \
            acc2[0][nf] = mfma(hA[0][kf], bw, acc2[0][nf]);                             \
            acc2[1][nf] = mfma(hA[1][kf], bw, acc2[1][nf]);                             \
        }

// Build BN1 scale/shift into sc1L/sh1L (threads t<64)
#define BN1_SCALES                                                                      \
    if (t < 64) {                                                                       \
        float s = 0.f, sq = 0.f;                                                        \
        _Pragma("unroll")                                                               \
        for (int r = 0; r < 8; ++r) { s += stats1[r * 128 + t]; sq += stats1[r * 128 + 64 + t]; } \
        float mu = s * (1.f / S1f);                                                     \
        float var = sq * (1.f / S1f) - mu * mu;                                         \
        float rs = rsqrtf(var + EPSV);                                                  \
        float sc = g1[t] * rs;                                                          \
        sc1L[t] = sc;                                                                   \
        sh1L[t] = b1[t] - mu * sc;                                                      \
    }

// ---------------- s1: gather + L1 + stats1 + packed pre-h1 store ----------------
__global__ __launch_bounds__(256, 6) void k_s1(const int* __restrict__ gidx,
                                               const float* __restrict__ src_xyz,
                                               const float* __restrict__ xyz,
                                               const short* __restrict__ src_xb,
                                               const short* __restrict__ w1b,
                                               float* __restrict__ stats1,
                                               short* __restrict__ h1p) {
    __shared__ short wbuf[4][2336];
    __shared__ float redS[256], redQ[256];
    int t = threadIdx.x, lane = t & 63, w = t >> 6, ln = lane & 15, qq = lane >> 4;
    int g = blockIdx.x * 4 + w, b = g >> 10, m = g & 1023;
    float qx = xyz[((size_t)b * MM + m) * 3 + 0];
    float qy = xyz[((size_t)b * MM + m) * 3 + 1];
    float qz = xyz[((size_t)b * MM + m) * 3 + 2];
    short* R = wbuf[w];
    GATHER_WAVE(R)
    f32x4 acc1[2][4];
    L1_PHASE(R, acc1)
    // packed lane-major store: 4 x b128, 1KB contiguous per wave-instruction
    {
        short* hb = h1p + (size_t)g * 2048;
#pragma unroll
        for (int i = 0; i < 4; ++i) {
            int rf = i >> 1, p = i & 1;
            *(short8*)(hb + (i * 64 + lane) * 8) = pack8(acc1[rf][2 * p], acc1[rf][2 * p + 1]);
        }
    }
#pragma unroll
    for (int nf = 0; nf < 4; ++nf) {
        float s = 0.f, q = 0.f;
#pragma unroll
        for (int rf = 0; rf < 2; ++rf)
#pragma unroll
            for (int jj = 0; jj < 4; ++jj) { float v = acc1[rf][nf][jj]; s += v; q += v * v; }
        s += __shfl_xor(s, 16); s += __shfl_xor(s, 32);
        q += __shfl_xor(q, 16); q += __shfl_xor(q, 32);
        if (lane < 16) { redS[w * 64 + nf * 16 + lane] = s; redQ[w * 64 + nf * 16 + lane] = q; }
    }
    __syncthreads();
    if (t < 64) {
        float s = redS[t] + redS[64 + t] + redS[128 + t] + redS[192 + t];
        float q = redQ[t] + redQ[64 + t] + redQ[128 + t] + redQ[192 + t];
        float* st = stats1 + (blockIdx.x & 7) * 128;
        atomicAdd(&st[t], s);
        atomicAdd(&st[64 + t], q);
    }
}

// ---------------- s2: coalesced pre-h1 read -> BN1+gelu -> L2 -> stats2 ----------------
__global__ __launch_bounds__(256, 4) void k_s2(const short* __restrict__ h1p,
                                               const short* __restrict__ w2b,
                                               const float* __restrict__ g1,
                                               const float* __restrict__ b1,
                                               const float* __restrict__ stats1,
                                               float* __restrict__ stats2) {
    __shared__ short wbuf[4][2336];
    __shared__ float sc1L[64], sh1L[64];
    __shared__ float redS[512], redQ[512];
    int t = threadIdx.x, lane = t & 63, w = t >> 6, ln = lane & 15, qq = lane >> 4;
    int g = blockIdx.x * 4 + w;
    const short* hb = h1p + (size_t)g * 2048;
    short8 hv[4];
#pragma unroll
    for (int i = 0; i < 4; ++i) hv[i] = *(const short8*)(hb + (i * 64 + lane) * 8);
    BN1_SCALES
    __syncthreads();  // sc1L ready
    short* R = wbuf[w];
    H1_FROM_PACKED(R, hv)
    f32x4 acc2[2][8];
    L2_PHASE(R, acc2)
#pragma unroll
    for (int nf = 0; nf < 8; ++nf) {
        float s = 0.f, q = 0.f;
#pragma unroll
        for (int rf = 0; rf < 2; ++rf)
#pragma unroll
            for (int jj = 0; jj < 4; ++jj) { float v = acc2[rf][nf][jj]; s += v; q += v * v; }
        s += __shfl_xor(s, 16); s += __shfl_xor(s, 32);
        q += __shfl_xor(q, 16); q += __shfl_xor(q, 32);
        if (lane < 16) { redS[w * 128 + nf * 16 + lane] = s; redQ[w * 128 + nf * 16 + lane] = q; }
    }
    __syncthreads();
    if (t < 128) {
        float s = redS[t] + redS[128 + t] + redS[256 + t] + redS[384 + t];
        float q = redQ[t] + redQ[128 + t] + redQ[256 + t] + redQ[384 + t];
        float* st = stats2 + (blockIdx.x & 7) * 256;
        atomicAdd(&st[t], s);
        atomicAdd(&st[128 + t], q);
    }
}

// ---------------- k3: pre-h1 read -> L2 recompute -> L3 + max (1 barrier) ----------------
__global__ __launch_bounds__(256, 4) void k3(const short* __restrict__ h1p,
                                             const short* __restrict__ w2b,
                                             const short* __restrict__ w3b,
                                             const float* __restrict__ g1,
                                             const float* __restrict__ b1,
                                             const float* __restrict__ g2,
                                             const float* __restrict__ b2,
                                             const float* __restrict__ stats1,
                                             const float* __restrict__ stats2,
                                             float* __restrict__ out) {
    __shared__ short wbuf[4][4352];   // per-wave: h1 (stride 72) -> h2 (stride 136)
    __shared__ float sc1L[64], sh1L[64], sc2L[128], sh2L[128];
    int t = threadIdx.x, lane = t & 63, w = t >> 6, ln = lane & 15, qq = lane >> 4;
    int g = blockIdx.x * 4 + w;
    const short* hb = h1p + (size_t)g * 2048;
    short8 hv[4];
#pragma unroll
    for (int i = 0; i < 4; ++i) hv[i] = *(const short8*)(hb + (i * 64 + lane) * 8);
    BN1_SCALES
    if (t < 128) {
        float s = 0.f, sq = 0.f;
#pragma unroll
        for (int r = 0; r < 8; ++r) { s += stats2[r * 256 + t]; sq += stats2[r * 256 + 128 + t]; }
        float mu = s * (1.f / S1f);
        float var = sq * (1.f / S1f) - mu * mu;
        float rs = rsqrtf(var + EPSV);
        float sc = g2[t] * rs;
        sc2L[t] = sc;
        sh2L[t] = b2[t] - mu * sc;
    }
    __syncthreads();  // the only barrier: scales ready
    short* R = wbuf[w];
    H1_FROM_PACKED(R, hv)
    f32x4 acc2[2][8];
    L2_PHASE(R, acc2)
    // h2 epilogue (stride 136; hA frags already consumed)
#pragma unroll
    for (int rf = 0; rf < 2; ++rf)
#pragma unroll
        for (int nf = 0; nf < 8; ++nf) {
            int col = nf * 16 + ln;
            float sc = sc2L[col], sh = sh2L[col];
            int row0 = rf * 16 + qq * 4;
#pragma unroll
            for (int jj = 0; jj < 4; ++jj)
                R[(row0 + jj) * 136 + col] = f2b(gelu_t(acc2[rf][nf][jj] * sc + sh));
        }
    // L3: 8 aligned b128 h2 frag loads; w3 frags from global (L2-resident)
    short8 h2f[2][4];
#pragma unroll
    for (int rf = 0; rf < 2; ++rf)
#pragma unroll
        for (int kf = 0; kf < 4; ++kf)
            h2f[rf][kf] = *(const short8*)(R + (rf * 16 + ln) * 136 + kf * 32 + qq * 8);
#pragma unroll
    for (int nc = 0; nc < 4; ++nc) {
        f32x4 acc3[2][4];
#pragma unroll
        for (int rf = 0; rf < 2; ++rf)
#pragma unroll
            for (int nf = 0; nf < 4; ++nf) acc3[rf][nf] = zero4();
#pragma unroll
        for (int kf = 0; kf < 4; ++kf)
#pragma unroll
            for (int nf = 0; nf < 4; ++nf) {
                short8 bw = *(const short8*)(w3b + (size_t)(nc * 64 + nf * 16 + ln) * 128 + kf * 32 + qq * 8);
                acc3[0][nf] = mfma(h2f[0][kf], bw, acc3[0][nf]);
                acc3[1][nf] = mfma(h2f[1][kf], bw, acc3[1][nf]);
            }
#pragma unroll
        for (int nf = 0; nf < 4; ++nf) {
            float v = fmaxf(fmaxf(fmaxf(acc3[0][nf][0], acc3[0][nf][1]), fmaxf(acc3[0][nf][2], acc3[0][nf][3])),
                            fmaxf(fmaxf(acc3[1][nf][0], acc3[1][nf][1]), fmaxf(acc3[1][nf][2], acc3[1][nf][3])));
            v = fmaxf(v, __shfl_xor(v, 16));
            v = fmaxf(v, __shfl_xor(v, 32));
            if (lane < 16) out[(size_t)g * 256 + nc * 64 + nf * 16 + lane] = v;
        }
    }
}

// ---------------- stats3 + final BN/GELU ----------------
__global__ __launch_bounds__(256) void k_stats3(const float* __restrict__ out,
                                                float* __restrict__ stats3) {
    int t = threadIdx.x;
    float s = 0.f, q = 0.f;
    const float* p = out + (size_t)blockIdx.x * 128 * 256 + t;
    for (int r = 0; r < 128; ++r) { float v = p[r * 256]; s += v; q += v * v; }
    atomicAdd(&stats3[t], s);
    atomicAdd(&stats3[256 + t], q);
}

__global__ __launch_bounds__(256) void k_bn3(float* __restrict__ out,
                                             const float* __restrict__ stats3,
                                             const float* __restrict__ gl,
                                             const float* __restrict__ bl) {
    int i = blockIdx.x * 256 + threadIdx.x;
    int o = i & 255;
    float mu = stats3[o] * (1.f / S3f);
    float var = stats3[256 + o] * (1.f / S3f) - mu * mu;
    float rs = rsqrtf(var + EPSV);
    float x = out[i];
    out[i] = gelu_e((x - mu) * rs * gl[o] + bl[o]);
}

extern "C" void kernel_launch(void* const* d_in, const int* in_sizes, int n_in,
                              void* d_out, int out_size, void* d_ws, size_t ws_size,
                              hipStream_t stream) {
    const float* src_x   = (const float*)d_in[0];
    const float* src_xyz = (const float*)d_in[1];
    const float* xyz     = (const float*)d_in[2];
    const float* w1      = (const float*)d_in[3];
    const float* g1      = (const float*)d_in[4];
    const float* b1      = (const float*)d_in[5];
    const float* w2      = (const float*)d_in[6];
    const float* g2      = (const float*)d_in[7];
    const float* b2      = (const float*)d_in[8];
    const float* w3      = (const float*)d_in[9];
    const float* gl      = (const float*)d_in[10];
    const float* bl      = (const float*)d_in[11];
    float* out = (float*)d_out;

    int* gidx = (int*)d_ws;                              // 2 MB
    float* statsF = (float*)(gidx + BB * MM * KNN);
    float* stats1 = statsF;          // 8 x (64 sum | 64 sq)
    float* stats2 = statsF + 1024;   // 8 x (128 sum | 128 sq)
    float* stats3 = statsF + 3072;   // 256 sum + 256 sq
    short* wb = (short*)(statsF + 3584);
    short* w1b = wb;                 // [64][96] reordered
    short* w2b = wb + 6144;          // [128][64]
    short* w3b = wb + 14336;         // [256][128]
    short* src_xb = wb + 47104;      // [B][N][64] bf16  (ends ~10.6 MB)
    // materialized pre-BN h1, lane-major packed, 64 MB at 16 MB offset
    // (ws >= 144 MB proven in round 9; NEED here = 80 MB)
    short* h1p = (short*)((char*)d_ws + (size_t)(16u << 20));

    hipMemsetAsync(statsF, 0, 3584 * sizeof(float), stream);
    k_prep<<<2232, 256, 0, stream>>>(src_x, w1, w2, w3, src_xb, w1b, w2b, w3b);
    k_ballquery<<<(BB * MM) / 16, 256, 0, stream>>>(src_xyz, xyz, gidx);
    k_s1<<<(BB * MM) / 4, 256, 0, stream>>>(gidx, src_xyz, xyz, src_xb, w1b, stats1, h1p);
    k_s2<<<(BB * MM) / 4, 256, 0, stream>>>(h1p, w2b, g1, b1, stats1, stats2);
    k3<<<(BB * MM) / 4, 256, 0, stream>>>(h1p, w2b, w3b, g1, b1, g2, b2, stats1, stats2, out);
    k_stats3<<<(BB * MM) / 128, 256, 0, stream>>>(out, stats3);
    k_bn3<<<BB * MM, 256, 0, stream>>>(out, stats3, gl, bl);
}